// Round 1
// baseline (411.938 us; speedup 1.0000x reference)
//
#include <hip/hip_runtime.h>

// Problem constants (fixed by the reference)
#define Bdim   8
#define Cdim   2
#define Fdim   1024
#define Tdim   1024
#define NB     64
#define BWb    16
#define EMB    128
#define FEAT   64      // C * BW * 2
#define TILE_T 64
#define NTHR   256
#define EPSV   1e-5f

// Grid: Bdim * NB * (Tdim/TILE_T) = 8*64*16 = 8192 blocks of 256 threads.
// Each block: one (b, n) band and 64 consecutive t values.
// LDS: xs[f][t] 16KB + wt[f][e] 32KB + small ≈ 50KB -> 3 blocks/CU.
__global__ __launch_bounds__(NTHR, 3) void bandsplit_kernel(
    const float* __restrict__ xr, const float* __restrict__ xi,
    const float* __restrict__ lnw, const float* __restrict__ lnb,
    const float* __restrict__ fcw, const float* __restrict__ fcb,
    float* __restrict__ out)
{
    __shared__ float xs[FEAT][TILE_T];   // 64*64*4  = 16 KB, [feature][t]
    __shared__ float wt[FEAT][EMB];      // 64*128*4 = 32 KB, [feature][emb]
    __shared__ float sb[EMB];            // fc bias
    __shared__ float slnw[FEAT];
    __shared__ float slnb[FEAT];
    __shared__ float smu[TILE_T];
    __shared__ float srs[TILE_T];

    const int tid = threadIdx.x;
    const int bid = blockIdx.x;
    const int tb  = bid & 15;          // t-tile
    const int n   = (bid >> 4) & 63;   // band
    const int b   = bid >> 10;         // batch
    const int t0g = tb * TILE_T;

    // ---- stage per-band weights (contiguous float4 copies) ----
    {
        const float4* wsrc = (const float4*)(fcw + (size_t)n * FEAT * EMB);
        float4* wdst = (float4*)&wt[0][0];
#pragma unroll
        for (int k = 0; k < 8; ++k)
            wdst[tid + k * NTHR] = wsrc[tid + k * NTHR];

        if (tid < EMB)            sb[tid]         = fcb[n * EMB + tid];
        else if (tid < EMB + 64)  slnw[tid - EMB] = lnw[n * FEAT + (tid - EMB)];
        else if (tid < EMB + 128) slnb[tid - EMB - 64] = lnb[n * FEAT + (tid - EMB - 64)];
    }

    // ---- stage x tile: xs[f][t], f = c*32 + w*2 + r, freq = n*16 + w ----
    // 64 rows * 64 t = 1024 float4 -> 4 per thread; lanes walk t (coalesced).
#pragma unroll
    for (int k = 0; k < 4; ++k) {
        const int v  = tid + k * NTHR;      // 0..1023
        const int f  = v >> 4;              // 0..63
        const int tq = v & 15;              // float4 chunk within row
        const int c  = f >> 5;
        const int w  = (f >> 1) & 15;
        const float* src = ((f & 1) ? xi : xr)
            + (((size_t)(b * Cdim + c) * Fdim + (n * BWb + w)) * Tdim + t0g + tq * 4);
        *(float4*)&xs[f][tq * 4] = *(const float4*)src;
    }
    __syncthreads();

    // ---- per-row stats: 4 lanes per t row, 16 features each, shuffle-combine ----
    {
        const int t = tid >> 2;
        const int p = tid & 3;
        float s = 0.f, ss = 0.f;
#pragma unroll
        for (int j = 0; j < 16; ++j) {
            const float v = xs[p * 16 + j][t];
            s += v; ss += v * v;
        }
        s += __shfl_xor(s, 1); ss += __shfl_xor(ss, 1);
        s += __shfl_xor(s, 2); ss += __shfl_xor(ss, 2);
        if (p == 0) {
            const float mu  = s * (1.f / 64.f);
            const float var = ss * (1.f / 64.f) - mu * mu;
            smu[t] = mu;
            srs[t] = rsqrtf(var + EPSV);
        }
    }
    __syncthreads();

    // ---- normalize in place, fold in ln_w/ln_b ----
#pragma unroll
    for (int k = 0; k < 4; ++k) {
        const int v  = tid + k * NTHR;
        const int f  = v >> 4;
        const int tq = v & 15;
        float4 x  = *(float4*)&xs[f][tq * 4];
        const float4 mu = *(const float4*)&smu[tq * 4];
        const float4 rs = *(const float4*)&srs[tq * 4];
        const float gw = slnw[f], gb = slnb[f];
        x.x = (x.x - mu.x) * rs.x * gw + gb;
        x.y = (x.y - mu.y) * rs.y * gw + gb;
        x.z = (x.z - mu.z) * rs.z * gw + gb;
        x.w = (x.w - mu.w) * rs.w * gw + gb;
        *(float4*)&xs[f][tq * 4] = x;
    }
    __syncthreads();

    // ---- register-tiled GEMM: out[t][e] = sum_f xs[f][t] * wt[f][e] ----
    // thread tile: 4 t x 8 e  (16 tq groups x 16 eq groups)
    const int t0 = (tid >> 4) * 4;   // 0..60
    const int e0 = (tid & 15) * 8;   // 0..120

    float acc[4][8];
#pragma unroll
    for (int i = 0; i < 4; ++i)
#pragma unroll
        for (int j = 0; j < 8; ++j) acc[i][j] = 0.f;

#pragma unroll 4
    for (int f = 0; f < FEAT; ++f) {
        const float4 av = *(const float4*)&xs[f][t0];
        const float4 b0 = *(const float4*)&wt[f][e0];
        const float4 b1 = *(const float4*)&wt[f][e0 + 4];
        const float a[4]  = {av.x, av.y, av.z, av.w};
        const float bb[8] = {b0.x, b0.y, b0.z, b0.w, b1.x, b1.y, b1.z, b1.w};
#pragma unroll
        for (int i = 0; i < 4; ++i)
#pragma unroll
            for (int j = 0; j < 8; ++j)
                acc[i][j] = fmaf(a[i], bb[j], acc[i][j]);
    }

    // ---- epilogue: add bias, coalesced float4 stores ----
    const float4 bias0 = *(const float4*)&sb[e0];
    const float4 bias1 = *(const float4*)&sb[e0 + 4];
    const size_t obase = (((size_t)(b * NB + n)) * Tdim + (t0g + t0)) * EMB + e0;
#pragma unroll
    for (int i = 0; i < 4; ++i) {
        float4 o0, o1;
        o0.x = acc[i][0] + bias0.x; o0.y = acc[i][1] + bias0.y;
        o0.z = acc[i][2] + bias0.z; o0.w = acc[i][3] + bias0.w;
        o1.x = acc[i][4] + bias1.x; o1.y = acc[i][5] + bias1.y;
        o1.z = acc[i][6] + bias1.z; o1.w = acc[i][7] + bias1.w;
        *(float4*)(out + obase + (size_t)i * EMB)     = o0;
        *(float4*)(out + obase + (size_t)i * EMB + 4) = o1;
    }
}

extern "C" void kernel_launch(void* const* d_in, const int* in_sizes, int n_in,
                              void* d_out, int out_size, void* d_ws, size_t ws_size,
                              hipStream_t stream) {
    const float* xr  = (const float*)d_in[0];
    const float* xi  = (const float*)d_in[1];
    const float* lnw = (const float*)d_in[2];
    const float* lnb = (const float*)d_in[3];
    const float* fcw = (const float*)d_in[4];
    const float* fcb = (const float*)d_in[5];
    float* out = (float*)d_out;

    const int grid = Bdim * NB * (Tdim / TILE_T);   // 8192
    hipLaunchKernelGGL(bandsplit_kernel, dim3(grid), dim3(NTHR), 0, stream,
                       xr, xi, lnw, lnb, fcw, fcb, out);
}